// Round 7
// baseline (1575.826 us; speedup 1.0000x reference)
//
#include <hip/hip_runtime.h>
#include <hip/hip_cooperative_groups.h>

namespace cg = cooperative_groups;

#define N_NODES 500000
#define N_EDGES 8000000
#define FEAT 10
#define HID 32
#define N_TOOLS 13
#define N_PRIM 8

// ---- two-level bucketing: (src octant, dst bucket) -------------------------
#define BK_BITS 9
#define BK_SIZE (1 << BK_BITS)                         // 512 nodes / bucket
#define NB ((N_NODES + BK_SIZE - 1) / BK_SIZE)         // 977
#define N_OCT 8                                        // src>>16 in [0,8)
#define NB2 (N_OCT * NB)                               // 7816 sub-buckets
#define SB_THREADS 512
#define SB_EPT 64
#define SB_CHUNK (SB_THREADS * SB_EPT)                 // 32768 edges / block
#define SB_BLOCKS ((N_EDGES + SB_CHUNK - 1) / SB_CHUNK)  // 245
#define R_CH 7
#define ROWS_PER_CH ((SB_BLOCKS + R_CH - 1) / R_CH)    // 35
#define CC_BLOCKS ((NB2 + 255) / 256)                  // 31
#define CPT ((NB2 + 255) / 256)                        // 31 cols/thread in scan_b

// ===========================================================================
// 1) per-block sub-bucket histogram (LDS only)
// ===========================================================================
__global__ __launch_bounds__(SB_THREADS) void bhist2_kernel(
    const int* __restrict__ src, const int* __restrict__ dst,
    int* __restrict__ bhist) {
    __shared__ int hist[NB2];  // 31.3 KB
    const int t = threadIdx.x;
    for (int i = t; i < NB2; i += SB_THREADS) hist[i] = 0;
    __syncthreads();
    const int base = blockIdx.x * SB_CHUNK;
    for (int k = 0; k < SB_EPT; ++k) {
        int e = base + k * SB_THREADS + t;  // coalesced
        if (e < N_EDGES) {
            int sub = (src[e] >> 16) * NB + (dst[e] >> BK_BITS);
            atomicAdd(&hist[sub], 1);
        }
    }
    __syncthreads();
    int* row = bhist + (size_t)blockIdx.x * NB2;
    for (int i = t; i < NB2; i += SB_THREADS) row[i] = hist[i];
}

// ===========================================================================
// 2a) column partial sums over row chunks
// ===========================================================================
__global__ __launch_bounds__(256) void scan_a_kernel(
    const int* __restrict__ bhist, int* __restrict__ ctmp) {
    const int rc = blockIdx.x / CC_BLOCKS;
    const int cc = blockIdx.x % CC_BLOCKS;
    const int c = cc * 256 + threadIdx.x;
    if (c >= NB2) return;
    const int r0 = rc * ROWS_PER_CH;
    const int r1 = (r0 + ROWS_PER_CH < SB_BLOCKS) ? r0 + ROWS_PER_CH : SB_BLOCKS;
    int s = 0;
    for (int r = r0; r < r1; ++r) s += bhist[(size_t)r * NB2 + c];  // coalesced
    ctmp[rc * NB2 + c] = s;
}

// ===========================================================================
// 2b) exclusive scan of 7816 column totals (parallel) + per-chunk starts
// ===========================================================================
__global__ __launch_bounds__(256) void scan_b_kernel(
    const int* __restrict__ ctmp, int* __restrict__ substart,
    int* __restrict__ cstart) {
    __shared__ int coltot[NB2];  // 31.3 KB
    __shared__ int tsum[256];
    const int t = threadIdx.x;
    const int c0 = t * CPT;
    const int c1 = (c0 + CPT < NB2) ? c0 + CPT : NB2;
    int s = 0;
    for (int c = c0; c < c1; ++c) {
        int v = 0;
#pragma unroll
        for (int rc = 0; rc < R_CH; ++rc) v += ctmp[rc * NB2 + c];
        coltot[c] = v;
        s += v;
    }
    tsum[t] = s;
    __syncthreads();
    if (t == 0) {
        int run = 0;
        for (int i = 0; i < 256; ++i) {
            int v = tsum[i];
            tsum[i] = run;
            run += v;
        }
    }
    __syncthreads();
    int run = tsum[t];
    for (int c = c0; c < c1; ++c) {
        substart[c] = run;
        int r2 = run;
#pragma unroll
        for (int rc = 0; rc < R_CH; ++rc) {
            cstart[rc * NB2 + c] = r2;
            r2 += ctmp[rc * NB2 + c];
        }
        run += coltot[c];
    }
    if (t == 255) substart[NB2] = run;  // == N_EDGES
}

// ===========================================================================
// 2c) per-(block,sub-bucket) exact offsets, in place in bhist
// ===========================================================================
__global__ __launch_bounds__(256) void scan_c_kernel(
    int* __restrict__ bhist, const int* __restrict__ cstart) {
    const int rc = blockIdx.x / CC_BLOCKS;
    const int cc = blockIdx.x % CC_BLOCKS;
    const int c = cc * 256 + threadIdx.x;
    if (c >= NB2) return;
    const int r0 = rc * ROWS_PER_CH;
    const int r1 = (r0 + ROWS_PER_CH < SB_BLOCKS) ? r0 + ROWS_PER_CH : SB_BLOCKS;
    int run = cstart[rc * NB2 + c];
    for (int r = r0; r < r1; ++r) {
        size_t i = (size_t)r * NB2 + c;
        int v = bhist[i];
        bhist[i] = run;
        run += v;
    }
}

// ===========================================================================
// 3) multisplit scatter into (oct, bucket) order:
//    store[pos] = src_low16 | (dst_local9 << 16)
// ===========================================================================
__global__ __launch_bounds__(SB_THREADS) void mscatter2_kernel(
    const int* __restrict__ src, const int* __restrict__ dst,
    const int* __restrict__ bhist, int* __restrict__ store) {
    __shared__ int cursor[NB2];  // running global cursors, 31.3 KB
    const int t = threadIdx.x;
    const int* row = bhist + (size_t)blockIdx.x * NB2;
    for (int i = t; i < NB2; i += SB_THREADS) cursor[i] = row[i];
    __syncthreads();
    const int base = blockIdx.x * SB_CHUNK;
    for (int k = 0; k < SB_EPT; ++k) {
        int e = base + k * SB_THREADS + t;
        if (e < N_EDGES) {
            int d = dst[e];
            int s = src[e];
            int sub = (s >> 16) * NB + (d >> BK_BITS);
            int pos = atomicAdd(&cursor[sub], 1);  // LDS atomic
            store[pos] = (s & 0xFFFF) | ((d & (BK_SIZE - 1)) << 16);
        }
    }
}

// ===========================================================================
// 4) cooperative aggregation: 8 src-octant phases with grid.sync() between —
//    lagg/lcnt persist in LDS (no agg global traffic), per-phase streaming
//    ~0.5 MB/XCD so the 2.6 MB x-octant stays L2-resident. Then fused node
//    transform + graph-embed partial reduction.
// ===========================================================================
__global__ __launch_bounds__(256, 4) void coop_aggr_kernel(
    const int* __restrict__ substart, const int* __restrict__ store,
    const float* __restrict__ x,
    const float* __restrict__ w_self, const float* __restrict__ b_self,
    const float* __restrict__ w_neigh, const float* __restrict__ b_neigh,
    float* __restrict__ h_out, float* __restrict__ hsum) {
    cg::grid_group grid = cg::this_grid();
    __shared__ float lagg[BK_SIZE * FEAT];  // 20 KB
    __shared__ float lcnt[BK_SIZE];         // 2 KB
    __shared__ float red[4][HID];
    const int t = threadIdx.x;
    const int b = blockIdx.x;
    const int j = t & 31;
    float ws[FEAT], wn[FEAT];
#pragma unroll
    for (int k = 0; k < FEAT; ++k) {
        ws[k] = w_self[k * HID + j];
        wn[k] = w_neigh[k * HID + j];
    }
    const float bias = b_self[j] + b_neigh[j];

    for (int i = t; i < BK_SIZE * FEAT; i += 256) lagg[i] = 0.0f;
    for (int i = t; i < BK_SIZE; i += 256) lcnt[i] = 0.0f;
    __syncthreads();

    for (int oct = 0; oct < N_OCT; ++oct) {
        const int s0 = substart[oct * NB + b];
        const int e0 = substart[oct * NB + b + 1];
        for (int o = s0 + t; o < e0; o += 256) {
            int v = store[o];  // coalesced
            int s = (oct << 16) | (v & 0xFFFF);
            int loc = (v >> 16) & (BK_SIZE - 1);
            const float2* xr = (const float2*)(x + (size_t)s * FEAT);
            float2 p0 = xr[0], p1 = xr[1], p2 = xr[2], p3 = xr[3], p4 = xr[4];
            float* la = lagg + loc * FEAT;
            atomicAdd(&la[0], p0.x); atomicAdd(&la[1], p0.y);
            atomicAdd(&la[2], p1.x); atomicAdd(&la[3], p1.y);
            atomicAdd(&la[4], p2.x); atomicAdd(&la[5], p2.y);
            atomicAdd(&la[6], p3.x); atomicAdd(&la[7], p3.y);
            atomicAdd(&la[8], p4.x); atomicAdd(&la[9], p4.y);
            atomicAdd(&lcnt[loc], 1.0f);
        }
        if (oct < N_OCT - 1) grid.sync();  // phase boundary: keep octant L2-hot
    }
    __syncthreads();

    const int node0 = b << BK_BITS;
    const int lim = (N_NODES - node0 < BK_SIZE) ? (N_NODES - node0) : BK_SIZE;
    float partial = 0.0f;
#pragma unroll 4
    for (int k = 0; k < (BK_SIZE * HID) / 256; ++k) {
        int idx = (k << 8) + t;  // (node_local, j) pairs
        int nl = idx >> 5;
        if (nl < lim) {
            float inv = 1.0f / fmaxf(lcnt[nl], 1.0f);
            const float* xr = x + (size_t)(node0 + nl) * FEAT;
            const float* la = lagg + nl * FEAT;
            float acc = bias;
#pragma unroll
            for (int kk = 0; kk < FEAT; ++kk)
                acc += xr[kk] * ws[kk] + la[kk] * inv * wn[kk];
            acc = fmaxf(acc, 0.0f);
            h_out[(size_t)node0 * HID + idx] = acc;  // coalesced
            partial += acc;
        }
    }

    partial += __shfl_down(partial, 32);
    const int wave = t >> 6, lane = t & 63;
    if (lane < 32) red[wave][lane] = partial;
    __syncthreads();
    if (t < 32) {
        float s2 = red[0][t] + red[1][t] + red[2][t] + red[3][t];
        atomicAdd(&hsum[t], s2);
    }
}

// ===========================================================================
// 4') non-cooperative fallback: identical but no grid.sync (correct, slower)
// ===========================================================================
__global__ __launch_bounds__(256, 4) void aggr_nosync_kernel(
    const int* __restrict__ substart, const int* __restrict__ store,
    const float* __restrict__ x,
    const float* __restrict__ w_self, const float* __restrict__ b_self,
    const float* __restrict__ w_neigh, const float* __restrict__ b_neigh,
    float* __restrict__ h_out, float* __restrict__ hsum) {
    __shared__ float lagg[BK_SIZE * FEAT];
    __shared__ float lcnt[BK_SIZE];
    __shared__ float red[4][HID];
    const int t = threadIdx.x;
    const int b = blockIdx.x;
    const int j = t & 31;
    float ws[FEAT], wn[FEAT];
#pragma unroll
    for (int k = 0; k < FEAT; ++k) {
        ws[k] = w_self[k * HID + j];
        wn[k] = w_neigh[k * HID + j];
    }
    const float bias = b_self[j] + b_neigh[j];

    for (int i = t; i < BK_SIZE * FEAT; i += 256) lagg[i] = 0.0f;
    for (int i = t; i < BK_SIZE; i += 256) lcnt[i] = 0.0f;
    __syncthreads();

    const int s0 = substart[0 * NB + b];
    const int e0 = substart[(N_OCT - 1) * NB + b + 1];
    // bucket b's edges are the union of its 8 sub-segments; walk each
    for (int oct = 0; oct < N_OCT; ++oct) {
        const int a0 = substart[oct * NB + b];
        const int a1 = substart[oct * NB + b + 1];
        for (int o = a0 + t; o < a1; o += 256) {
            int v = store[o];
            int s = (oct << 16) | (v & 0xFFFF);
            int loc = (v >> 16) & (BK_SIZE - 1);
            const float2* xr = (const float2*)(x + (size_t)s * FEAT);
            float2 p0 = xr[0], p1 = xr[1], p2 = xr[2], p3 = xr[3], p4 = xr[4];
            float* la = lagg + loc * FEAT;
            atomicAdd(&la[0], p0.x); atomicAdd(&la[1], p0.y);
            atomicAdd(&la[2], p1.x); atomicAdd(&la[3], p1.y);
            atomicAdd(&la[4], p2.x); atomicAdd(&la[5], p2.y);
            atomicAdd(&la[6], p3.x); atomicAdd(&la[7], p3.y);
            atomicAdd(&la[8], p4.x); atomicAdd(&la[9], p4.y);
            atomicAdd(&lcnt[loc], 1.0f);
        }
    }
    (void)s0; (void)e0;
    __syncthreads();

    const int node0 = b << BK_BITS;
    const int lim = (N_NODES - node0 < BK_SIZE) ? (N_NODES - node0) : BK_SIZE;
    float partial = 0.0f;
#pragma unroll 4
    for (int k = 0; k < (BK_SIZE * HID) / 256; ++k) {
        int idx = (k << 8) + t;
        int nl = idx >> 5;
        if (nl < lim) {
            float inv = 1.0f / fmaxf(lcnt[nl], 1.0f);
            const float* xr = x + (size_t)(node0 + nl) * FEAT;
            const float* la = lagg + nl * FEAT;
            float acc = bias;
#pragma unroll
            for (int kk = 0; kk < FEAT; ++kk)
                acc += xr[kk] * ws[kk] + la[kk] * inv * wn[kk];
            acc = fmaxf(acc, 0.0f);
            h_out[(size_t)node0 * HID + idx] = acc;
            partial += acc;
        }
    }

    partial += __shfl_down(partial, 32);
    const int wave = t >> 6, lane = t & 63;
    if (lane < 32) red[wave][lane] = partial;
    __syncthreads();
    if (t < 32) {
        float s2 = red[0][t] + red[1][t] + red[2][t] + red[3][t];
        atomicAdd(&hsum[t], s2);
    }
}

// ===========================================================================
// 5) heads
// ===========================================================================
__global__ void head_kernel(const float* __restrict__ hsum,
                            const float* __restrict__ w_act,
                            const float* __restrict__ b_act,
                            const float* __restrict__ w_prim,
                            const float* __restrict__ b_prim,
                            float* __restrict__ out) {
    __shared__ float ge[HID];
    const int t = threadIdx.x;
    if (t < HID) {
        const float g = hsum[t] * (1.0f / (float)N_NODES);
        ge[t] = g;
        out[N_TOOLS + N_PRIM + t] = g;
    }
    __syncthreads();
    if (t < N_TOOLS) {
        float a = b_act[t];
#pragma unroll
        for (int jj = 0; jj < HID; ++jj) a += ge[jj] * w_act[jj * N_TOOLS + t];
        out[t] = a;
    }
    if (t >= 32 && t < 32 + N_PRIM) {
        const int p = t - 32;
        float a = b_prim[p];
#pragma unroll
        for (int jj = 0; jj < HID; ++jj) a += ge[jj] * w_prim[jj * N_PRIM + p];
        out[N_TOOLS + p] = a;
    }
}

// ===========================================================================
// tiny-ws fallback (round-1 atomic path)
// ===========================================================================
__global__ void scatter_kernel(const int* __restrict__ src,
                               const int* __restrict__ dst,
                               const float* __restrict__ x,
                               float* __restrict__ agg,
                               float* __restrict__ cnt) {
    int e = blockIdx.x * blockDim.x + threadIdx.x;
    if (e >= N_EDGES) return;
    int s = src[e];
    int d = dst[e];
    const float* xr = x + (size_t)s * FEAT;
    float* ar = agg + (size_t)d * FEAT;
#pragma unroll
    for (int k = 0; k < FEAT; ++k) atomicAdd(&ar[k], xr[k]);
    atomicAdd(&cnt[d], 1.0f);
}

__global__ void node_kernel(const float* __restrict__ x,
                            const float* __restrict__ agg,
                            const float* __restrict__ cnt,
                            const float* __restrict__ w_self,
                            const float* __restrict__ b_self,
                            const float* __restrict__ w_neigh,
                            const float* __restrict__ b_neigh,
                            float* __restrict__ h_out,
                            float* __restrict__ hsum) {
    const int j = threadIdx.x & 31;
    float ws[FEAT], wn[FEAT];
#pragma unroll
    for (int k = 0; k < FEAT; ++k) {
        ws[k] = w_self[k * HID + j];
        wn[k] = w_neigh[k * HID + j];
    }
    const float bias = b_self[j] + b_neigh[j];
    const long total = (long)N_NODES * HID;
    const long stride = (long)gridDim.x * blockDim.x;
    float partial = 0.0f;
    for (long idx = (long)blockIdx.x * blockDim.x + threadIdx.x; idx < total;
         idx += stride) {
        const int i = (int)(idx >> 5);
        const float inv = 1.0f / fmaxf(cnt[i], 1.0f);
        const float* xr = x + (size_t)i * FEAT;
        const float* ar = agg + (size_t)i * FEAT;
        float acc = bias;
#pragma unroll
        for (int k = 0; k < FEAT; ++k) {
            acc += xr[k] * ws[k];
            acc += (ar[k] * inv) * wn[k];
        }
        acc = fmaxf(acc, 0.0f);
        h_out[idx] = acc;
        partial += acc;
    }
    partial += __shfl_down(partial, 32);
    __shared__ float red[4][HID];
    const int wave = threadIdx.x >> 6;
    const int lane = threadIdx.x & 63;
    if (lane < 32) red[wave][lane] = partial;
    __syncthreads();
    if (threadIdx.x < 32) {
        float s = red[0][threadIdx.x] + red[1][threadIdx.x] +
                  red[2][threadIdx.x] + red[3][threadIdx.x];
        atomicAdd(&hsum[threadIdx.x], s);
    }
}

extern "C" void kernel_launch(void* const* d_in, const int* in_sizes, int n_in,
                              void* d_out, int out_size, void* d_ws,
                              size_t ws_size, hipStream_t stream) {
    const float* x       = (const float*)d_in[0];
    const int*   ei      = (const int*)d_in[1];
    const float* w_self  = (const float*)d_in[2];
    const float* b_self  = (const float*)d_in[3];
    const float* w_neigh = (const float*)d_in[4];
    const float* b_neigh = (const float*)d_in[5];
    const float* w_act   = (const float*)d_in[6];
    const float* b_act   = (const float*)d_in[7];
    const float* w_prim  = (const float*)d_in[8];
    const float* b_prim  = (const float*)d_in[9];
    float* out = (float*)d_out;
    const int* src = ei;
    const int* dst = ei + N_EDGES;
    float* hout = out + (N_TOOLS + N_PRIM + HID);

    // ws layout (4B elems):
    //   bhist [SB_BLOCKS*NB2] | ctmp [R_CH*NB2] | cstart [R_CH*NB2]
    //   | substart [NB2+1] | store [E] | hsum [HID]       (~40.1 MB)
    const size_t n_bhist = (size_t)SB_BLOCKS * NB2;
    const size_t n_ctmp  = (size_t)R_CH * NB2;
    const size_t n_sub   = NB2 + 1;
    const size_t need =
        (n_bhist + 2 * n_ctmp + n_sub + (size_t)N_EDGES + HID) * 4;

    if (ws_size >= need) {
        int*   bhist    = (int*)d_ws;
        int*   ctmp     = bhist + n_bhist;
        int*   cstart   = ctmp + n_ctmp;
        int*   substart = cstart + n_ctmp;
        int*   store    = substart + n_sub;
        float* hsum     = (float*)(store + N_EDGES);

        hipMemsetAsync(hsum, 0, HID * sizeof(float), stream);

        bhist2_kernel<<<SB_BLOCKS, SB_THREADS, 0, stream>>>(src, dst, bhist);
        scan_a_kernel<<<R_CH * CC_BLOCKS, 256, 0, stream>>>(bhist, ctmp);
        scan_b_kernel<<<1, 256, 0, stream>>>(ctmp, substart, cstart);
        scan_c_kernel<<<R_CH * CC_BLOCKS, 256, 0, stream>>>(bhist, cstart);
        mscatter2_kernel<<<SB_BLOCKS, SB_THREADS, 0, stream>>>(src, dst, bhist,
                                                               store);

        const int* c_sub = substart;
        const int* c_store = store;
        void* kargs[] = {
            (void*)&c_sub,   (void*)&c_store, (void*)&x,
            (void*)&w_self,  (void*)&b_self,  (void*)&w_neigh,
            (void*)&b_neigh, (void*)&hout,    (void*)&hsum};
        hipError_t cerr = hipLaunchCooperativeKernel(
            (const void*)coop_aggr_kernel, dim3(NB), dim3(256), kargs, 0,
            stream);
        if (cerr != hipSuccess) {
            (void)hipGetLastError();  // clear sticky error, use fallback
            aggr_nosync_kernel<<<NB, 256, 0, stream>>>(
                substart, store, x, w_self, b_self, w_neigh, b_neigh, hout,
                hsum);
        }
        head_kernel<<<1, 64, 0, stream>>>(hsum, w_act, b_act, w_prim, b_prim,
                                          out);
    } else {
        float* agg  = (float*)d_ws;
        float* cnt  = agg + (size_t)N_NODES * FEAT;
        float* hsum = cnt + N_NODES;
        const size_t zero_bytes =
            ((size_t)N_NODES * FEAT + N_NODES + HID) * sizeof(float);
        hipMemsetAsync(d_ws, 0, zero_bytes, stream);

        scatter_kernel<<<(N_EDGES + 255) / 256, 256, 0, stream>>>(src, dst, x,
                                                                  agg, cnt);
        node_kernel<<<4096, 256, 0, stream>>>(x, agg, cnt, w_self, b_self,
                                              w_neigh, b_neigh, hout, hsum);
        head_kernel<<<1, 64, 0, stream>>>(hsum, w_act, b_act, w_prim, b_prim,
                                          out);
    }
}

// Round 8
// 976.464 us; speedup vs baseline: 1.6138x; 1.6138x over previous
//
#include <hip/hip_runtime.h>
#include <hip/hip_cooperative_groups.h>

#define N_NODES 500000
#define N_EDGES 8000000
#define FEAT 10
#define HID 32
#define N_TOOLS 13
#define N_PRIM 8

// ---- two-level bucketing: (src octant, dst bucket) -------------------------
#define BK_BITS 10
#define BK_SIZE (1 << BK_BITS)                         // 1024 nodes / bucket
#define NB ((N_NODES + BK_SIZE - 1) / BK_SIZE)         // 489
#define N_OCT 8                                        // src>>16 in [0,8)
#define NB2 (N_OCT * NB)                               // 3912 sub-buckets
#define LAGG_STRIDE 11                                 // odd: spreads 32 banks
#define SB_THREADS 512
#define SB_EPT 64
#define SB_CHUNK (SB_THREADS * SB_EPT)                 // 32768 edges / block
#define SB_BLOCKS ((N_EDGES + SB_CHUNK - 1) / SB_CHUNK)  // 245
#define R_CH 7
#define ROWS_PER_CH ((SB_BLOCKS + R_CH - 1) / R_CH)    // 35
#define CC_BLOCKS ((NB2 + 255) / 256)                  // 16
#define CPT ((NB2 + 255) / 256)                        // 16 cols/thread

// ===========================================================================
// 1) per-block sub-bucket histogram (LDS only)
// ===========================================================================
__global__ __launch_bounds__(SB_THREADS) void bhist2_kernel(
    const int* __restrict__ src, const int* __restrict__ dst,
    int* __restrict__ bhist) {
    __shared__ int hist[NB2];  // 15.6 KB
    const int t = threadIdx.x;
    for (int i = t; i < NB2; i += SB_THREADS) hist[i] = 0;
    __syncthreads();
    const int base = blockIdx.x * SB_CHUNK;
    for (int k = 0; k < SB_EPT; ++k) {
        int e = base + k * SB_THREADS + t;  // coalesced
        if (e < N_EDGES) {
            int sub = (src[e] >> 16) * NB + (dst[e] >> BK_BITS);
            atomicAdd(&hist[sub], 1);
        }
    }
    __syncthreads();
    int* row = bhist + (size_t)blockIdx.x * NB2;
    for (int i = t; i < NB2; i += SB_THREADS) row[i] = hist[i];
}

// ===========================================================================
// 2a) column partial sums over row chunks
// ===========================================================================
__global__ __launch_bounds__(256) void scan_a_kernel(
    const int* __restrict__ bhist, int* __restrict__ ctmp) {
    const int rc = blockIdx.x / CC_BLOCKS;
    const int cc = blockIdx.x % CC_BLOCKS;
    const int c = cc * 256 + threadIdx.x;
    if (c >= NB2) return;
    const int r0 = rc * ROWS_PER_CH;
    const int r1 = (r0 + ROWS_PER_CH < SB_BLOCKS) ? r0 + ROWS_PER_CH : SB_BLOCKS;
    int s = 0;
    for (int r = r0; r < r1; ++r) s += bhist[(size_t)r * NB2 + c];  // coalesced
    ctmp[rc * NB2 + c] = s;
}

// ===========================================================================
// 2b) exclusive scan of column totals (parallel) + per-chunk starts
// ===========================================================================
__global__ __launch_bounds__(256) void scan_b_kernel(
    const int* __restrict__ ctmp, int* __restrict__ substart,
    int* __restrict__ cstart) {
    __shared__ int coltot[NB2];  // 15.6 KB
    __shared__ int tsum[256];
    const int t = threadIdx.x;
    const int c0 = t * CPT;
    const int c1 = (c0 + CPT < NB2) ? c0 + CPT : NB2;
    int s = 0;
    for (int c = c0; c < c1; ++c) {
        int v = 0;
#pragma unroll
        for (int rc = 0; rc < R_CH; ++rc) v += ctmp[rc * NB2 + c];
        coltot[c] = v;
        s += v;
    }
    tsum[t] = s;
    __syncthreads();
    if (t == 0) {
        int run = 0;
        for (int i = 0; i < 256; ++i) {
            int v = tsum[i];
            tsum[i] = run;
            run += v;
        }
    }
    __syncthreads();
    int run = tsum[t];
    for (int c = c0; c < c1; ++c) {
        substart[c] = run;
        int r2 = run;
#pragma unroll
        for (int rc = 0; rc < R_CH; ++rc) {
            cstart[rc * NB2 + c] = r2;
            r2 += ctmp[rc * NB2 + c];
        }
        run += coltot[c];
    }
    if (t == 255) substart[NB2] = run;  // == N_EDGES
}

// ===========================================================================
// 2c) per-(block,sub-bucket) exact offsets, in place in bhist
// ===========================================================================
__global__ __launch_bounds__(256) void scan_c_kernel(
    int* __restrict__ bhist, const int* __restrict__ cstart) {
    const int rc = blockIdx.x / CC_BLOCKS;
    const int cc = blockIdx.x % CC_BLOCKS;
    const int c = cc * 256 + threadIdx.x;
    if (c >= NB2) return;
    const int r0 = rc * ROWS_PER_CH;
    const int r1 = (r0 + ROWS_PER_CH < SB_BLOCKS) ? r0 + ROWS_PER_CH : SB_BLOCKS;
    int run = cstart[rc * NB2 + c];
    for (int r = r0; r < r1; ++r) {
        size_t i = (size_t)r * NB2 + c;
        int v = bhist[i];
        bhist[i] = run;
        run += v;
    }
}

// ===========================================================================
// 3) multisplit scatter into (oct, bucket) order:
//    store[pos] = src_low16 | (dst_local10 << 16)
// ===========================================================================
__global__ __launch_bounds__(SB_THREADS) void mscatter2_kernel(
    const int* __restrict__ src, const int* __restrict__ dst,
    const int* __restrict__ bhist, int* __restrict__ store) {
    __shared__ int cursor[NB2];  // running global cursors, 15.6 KB
    const int t = threadIdx.x;
    const int* row = bhist + (size_t)blockIdx.x * NB2;
    for (int i = t; i < NB2; i += SB_THREADS) cursor[i] = row[i];
    __syncthreads();
    const int base = blockIdx.x * SB_CHUNK;
    for (int k = 0; k < SB_EPT; ++k) {
        int e = base + k * SB_THREADS + t;
        if (e < N_EDGES) {
            int d = dst[e];
            int s = src[e];
            int sub = (s >> 16) * NB + (d >> BK_BITS);
            int pos = atomicAdd(&cursor[sub], 1);  // LDS atomic
            store[pos] = (s & 0xFFFF) | ((d & (BK_SIZE - 1)) << 16);
        }
    }
}

// ===========================================================================
// soft phase barrier: NO memory ordering needed (no data crosses phases —
// it exists purely to keep all blocks gathering from the same x octant so
// the 2.6 MB octant stays L2-resident). Monotone counter, relaxed atomics.
// Safe only under cooperative launch (all blocks co-resident).
// ===========================================================================
__device__ __forceinline__ void soft_barrier(int* counter, int* release,
                                             int phase, int nblocks) {
    __syncthreads();
    if (threadIdx.x == 0) {
        __hip_atomic_fetch_add(counter, 1, __ATOMIC_RELAXED,
                               __HIP_MEMORY_SCOPE_AGENT);
        if (blockIdx.x == 0) {
            while (__hip_atomic_load(counter, __ATOMIC_RELAXED,
                                     __HIP_MEMORY_SCOPE_AGENT) <
                   nblocks * (phase + 1)) {
                __builtin_amdgcn_s_sleep(4);
            }
            __hip_atomic_store(release, phase + 1, __ATOMIC_RELAXED,
                               __HIP_MEMORY_SCOPE_AGENT);
        } else {
            while (__hip_atomic_load(release, __ATOMIC_RELAXED,
                                     __HIP_MEMORY_SCOPE_AGENT) < phase + 1) {
                __builtin_amdgcn_s_sleep(4);
            }
        }
    }
    __syncthreads();
}

// ===========================================================================
// 4) cooperative aggregation: 8 src-octant phases, soft barrier between.
//    lagg/lcnt persist in LDS; fused node transform + graph-embed partials.
// ===========================================================================
__global__ __launch_bounds__(256) void coop_aggr_kernel(
    const int* __restrict__ substart, const int* __restrict__ store,
    const float* __restrict__ x,
    const float* __restrict__ w_self, const float* __restrict__ b_self,
    const float* __restrict__ w_neigh, const float* __restrict__ b_neigh,
    float* __restrict__ h_out, float* __restrict__ hsum,
    int* bar_counter, int* bar_release) {
    __shared__ float lagg[BK_SIZE * LAGG_STRIDE];  // 44 KB (stride 11)
    __shared__ float lcnt[BK_SIZE];                // 4 KB
    __shared__ float red[4][HID];
    const int t = threadIdx.x;
    const int b = blockIdx.x;
    const int j = t & 31;
    float ws[FEAT], wn[FEAT];
#pragma unroll
    for (int k = 0; k < FEAT; ++k) {
        ws[k] = w_self[k * HID + j];
        wn[k] = w_neigh[k * HID + j];
    }
    const float bias = b_self[j] + b_neigh[j];

    for (int i = t; i < BK_SIZE * LAGG_STRIDE; i += 256) lagg[i] = 0.0f;
    for (int i = t; i < BK_SIZE; i += 256) lcnt[i] = 0.0f;
    __syncthreads();

    for (int oct = 0; oct < N_OCT; ++oct) {
        const int s0 = substart[oct * NB + b];
        const int e0 = substart[oct * NB + b + 1];
        for (int o = s0 + t; o < e0; o += 256) {
            int v = store[o];  // coalesced
            int s = (oct << 16) | (v & 0xFFFF);
            int loc = (v >> 16) & (BK_SIZE - 1);
            const float2* xr = (const float2*)(x + (size_t)s * FEAT);
            float2 p0 = xr[0], p1 = xr[1], p2 = xr[2], p3 = xr[3], p4 = xr[4];
            float* la = lagg + loc * LAGG_STRIDE;
            atomicAdd(&la[0], p0.x); atomicAdd(&la[1], p0.y);
            atomicAdd(&la[2], p1.x); atomicAdd(&la[3], p1.y);
            atomicAdd(&la[4], p2.x); atomicAdd(&la[5], p2.y);
            atomicAdd(&la[6], p3.x); atomicAdd(&la[7], p3.y);
            atomicAdd(&la[8], p4.x); atomicAdd(&la[9], p4.y);
            atomicAdd(&lcnt[loc], 1.0f);
        }
        if (oct < N_OCT - 1) soft_barrier(bar_counter, bar_release, oct, NB);
    }
    __syncthreads();

    const int node0 = b << BK_BITS;
    const int lim = (N_NODES - node0 < BK_SIZE) ? (N_NODES - node0) : BK_SIZE;
    float partial = 0.0f;
    for (int k = 0; k < (BK_SIZE * HID) / 256; ++k) {
        int idx = (k << 8) + t;  // (node_local, j) pairs
        int nl = idx >> 5;
        if (nl < lim) {
            float inv = 1.0f / fmaxf(lcnt[nl], 1.0f);
            const float* xr = x + (size_t)(node0 + nl) * FEAT;
            const float* la = lagg + nl * LAGG_STRIDE;
            float acc = bias;
#pragma unroll
            for (int kk = 0; kk < FEAT; ++kk)
                acc += xr[kk] * ws[kk] + la[kk] * inv * wn[kk];
            acc = fmaxf(acc, 0.0f);
            h_out[(size_t)node0 * HID + idx] = acc;  // coalesced
            partial += acc;
        }
    }

    partial += __shfl_down(partial, 32);
    const int wave = t >> 6, lane = t & 63;
    if (lane < 32) red[wave][lane] = partial;
    __syncthreads();
    if (t < 32) {
        float s2 = red[0][t] + red[1][t] + red[2][t] + red[3][t];
        atomicAdd(&hsum[t], s2);
    }
}

// ===========================================================================
// 4') non-cooperative fallback: identical, no barrier
// ===========================================================================
__global__ __launch_bounds__(256) void aggr_nosync_kernel(
    const int* __restrict__ substart, const int* __restrict__ store,
    const float* __restrict__ x,
    const float* __restrict__ w_self, const float* __restrict__ b_self,
    const float* __restrict__ w_neigh, const float* __restrict__ b_neigh,
    float* __restrict__ h_out, float* __restrict__ hsum) {
    __shared__ float lagg[BK_SIZE * LAGG_STRIDE];
    __shared__ float lcnt[BK_SIZE];
    __shared__ float red[4][HID];
    const int t = threadIdx.x;
    const int b = blockIdx.x;
    const int j = t & 31;
    float ws[FEAT], wn[FEAT];
#pragma unroll
    for (int k = 0; k < FEAT; ++k) {
        ws[k] = w_self[k * HID + j];
        wn[k] = w_neigh[k * HID + j];
    }
    const float bias = b_self[j] + b_neigh[j];

    for (int i = t; i < BK_SIZE * LAGG_STRIDE; i += 256) lagg[i] = 0.0f;
    for (int i = t; i < BK_SIZE; i += 256) lcnt[i] = 0.0f;
    __syncthreads();

    for (int oct = 0; oct < N_OCT; ++oct) {
        const int s0 = substart[oct * NB + b];
        const int e0 = substart[oct * NB + b + 1];
        for (int o = s0 + t; o < e0; o += 256) {
            int v = store[o];
            int s = (oct << 16) | (v & 0xFFFF);
            int loc = (v >> 16) & (BK_SIZE - 1);
            const float2* xr = (const float2*)(x + (size_t)s * FEAT);
            float2 p0 = xr[0], p1 = xr[1], p2 = xr[2], p3 = xr[3], p4 = xr[4];
            float* la = lagg + loc * LAGG_STRIDE;
            atomicAdd(&la[0], p0.x); atomicAdd(&la[1], p0.y);
            atomicAdd(&la[2], p1.x); atomicAdd(&la[3], p1.y);
            atomicAdd(&la[4], p2.x); atomicAdd(&la[5], p2.y);
            atomicAdd(&la[6], p3.x); atomicAdd(&la[7], p3.y);
            atomicAdd(&la[8], p4.x); atomicAdd(&la[9], p4.y);
            atomicAdd(&lcnt[loc], 1.0f);
        }
    }
    __syncthreads();

    const int node0 = b << BK_BITS;
    const int lim = (N_NODES - node0 < BK_SIZE) ? (N_NODES - node0) : BK_SIZE;
    float partial = 0.0f;
    for (int k = 0; k < (BK_SIZE * HID) / 256; ++k) {
        int idx = (k << 8) + t;
        int nl = idx >> 5;
        if (nl < lim) {
            float inv = 1.0f / fmaxf(lcnt[nl], 1.0f);
            const float* xr = x + (size_t)(node0 + nl) * FEAT;
            const float* la = lagg + nl * LAGG_STRIDE;
            float acc = bias;
#pragma unroll
            for (int kk = 0; kk < FEAT; ++kk)
                acc += xr[kk] * ws[kk] + la[kk] * inv * wn[kk];
            acc = fmaxf(acc, 0.0f);
            h_out[(size_t)node0 * HID + idx] = acc;
            partial += acc;
        }
    }

    partial += __shfl_down(partial, 32);
    const int wave = t >> 6, lane = t & 63;
    if (lane < 32) red[wave][lane] = partial;
    __syncthreads();
    if (t < 32) {
        float s2 = red[0][t] + red[1][t] + red[2][t] + red[3][t];
        atomicAdd(&hsum[t], s2);
    }
}

// ===========================================================================
// 5) heads
// ===========================================================================
__global__ void head_kernel(const float* __restrict__ hsum,
                            const float* __restrict__ w_act,
                            const float* __restrict__ b_act,
                            const float* __restrict__ w_prim,
                            const float* __restrict__ b_prim,
                            float* __restrict__ out) {
    __shared__ float ge[HID];
    const int t = threadIdx.x;
    if (t < HID) {
        const float g = hsum[t] * (1.0f / (float)N_NODES);
        ge[t] = g;
        out[N_TOOLS + N_PRIM + t] = g;
    }
    __syncthreads();
    if (t < N_TOOLS) {
        float a = b_act[t];
#pragma unroll
        for (int jj = 0; jj < HID; ++jj) a += ge[jj] * w_act[jj * N_TOOLS + t];
        out[t] = a;
    }
    if (t >= 32 && t < 32 + N_PRIM) {
        const int p = t - 32;
        float a = b_prim[p];
#pragma unroll
        for (int jj = 0; jj < HID; ++jj) a += ge[jj] * w_prim[jj * N_PRIM + p];
        out[N_TOOLS + p] = a;
    }
}

// ===========================================================================
// tiny-ws fallback (round-1 atomic path)
// ===========================================================================
__global__ void scatter_kernel(const int* __restrict__ src,
                               const int* __restrict__ dst,
                               const float* __restrict__ x,
                               float* __restrict__ agg,
                               float* __restrict__ cnt) {
    int e = blockIdx.x * blockDim.x + threadIdx.x;
    if (e >= N_EDGES) return;
    int s = src[e];
    int d = dst[e];
    const float* xr = x + (size_t)s * FEAT;
    float* ar = agg + (size_t)d * FEAT;
#pragma unroll
    for (int k = 0; k < FEAT; ++k) atomicAdd(&ar[k], xr[k]);
    atomicAdd(&cnt[d], 1.0f);
}

__global__ void node_kernel(const float* __restrict__ x,
                            const float* __restrict__ agg,
                            const float* __restrict__ cnt,
                            const float* __restrict__ w_self,
                            const float* __restrict__ b_self,
                            const float* __restrict__ w_neigh,
                            const float* __restrict__ b_neigh,
                            float* __restrict__ h_out,
                            float* __restrict__ hsum) {
    const int j = threadIdx.x & 31;
    float ws[FEAT], wn[FEAT];
#pragma unroll
    for (int k = 0; k < FEAT; ++k) {
        ws[k] = w_self[k * HID + j];
        wn[k] = w_neigh[k * HID + j];
    }
    const float bias = b_self[j] + b_neigh[j];
    const long total = (long)N_NODES * HID;
    const long stride = (long)gridDim.x * blockDim.x;
    float partial = 0.0f;
    for (long idx = (long)blockIdx.x * blockDim.x + threadIdx.x; idx < total;
         idx += stride) {
        const int i = (int)(idx >> 5);
        const float inv = 1.0f / fmaxf(cnt[i], 1.0f);
        const float* xr = x + (size_t)i * FEAT;
        const float* ar = agg + (size_t)i * FEAT;
        float acc = bias;
#pragma unroll
        for (int k = 0; k < FEAT; ++k) {
            acc += xr[k] * ws[k];
            acc += (ar[k] * inv) * wn[k];
        }
        acc = fmaxf(acc, 0.0f);
        h_out[idx] = acc;
        partial += acc;
    }
    partial += __shfl_down(partial, 32);
    __shared__ float red[4][HID];
    const int wave = threadIdx.x >> 6;
    const int lane = threadIdx.x & 63;
    if (lane < 32) red[wave][lane] = partial;
    __syncthreads();
    if (threadIdx.x < 32) {
        float s = red[0][threadIdx.x] + red[1][threadIdx.x] +
                  red[2][threadIdx.x] + red[3][threadIdx.x];
        atomicAdd(&hsum[threadIdx.x], s);
    }
}

extern "C" void kernel_launch(void* const* d_in, const int* in_sizes, int n_in,
                              void* d_out, int out_size, void* d_ws,
                              size_t ws_size, hipStream_t stream) {
    const float* x       = (const float*)d_in[0];
    const int*   ei      = (const int*)d_in[1];
    const float* w_self  = (const float*)d_in[2];
    const float* b_self  = (const float*)d_in[3];
    const float* w_neigh = (const float*)d_in[4];
    const float* b_neigh = (const float*)d_in[5];
    const float* w_act   = (const float*)d_in[6];
    const float* b_act   = (const float*)d_in[7];
    const float* w_prim  = (const float*)d_in[8];
    const float* b_prim  = (const float*)d_in[9];
    float* out = (float*)d_out;
    const int* src = ei;
    const int* dst = ei + N_EDGES;
    float* hout = out + (N_TOOLS + N_PRIM + HID);

    // ws layout (4B elems):
    //   bhist [SB_BLOCKS*NB2] | ctmp [R_CH*NB2] | cstart [R_CH*NB2]
    //   | substart [NB2+1] | store [E] | hsum [HID] | bar [2]   (~36 MB)
    const size_t n_bhist = (size_t)SB_BLOCKS * NB2;
    const size_t n_ctmp  = (size_t)R_CH * NB2;
    const size_t n_sub   = NB2 + 1;
    const size_t need =
        (n_bhist + 2 * n_ctmp + n_sub + (size_t)N_EDGES + HID + 2) * 4;

    if (ws_size >= need) {
        int*   bhist    = (int*)d_ws;
        int*   ctmp     = bhist + n_bhist;
        int*   cstart   = ctmp + n_ctmp;
        int*   substart = cstart + n_ctmp;
        int*   store    = substart + n_sub;
        float* hsum     = (float*)(store + N_EDGES);
        int*   bar      = (int*)(hsum + HID);  // [counter, release]

        hipMemsetAsync(hsum, 0, (HID + 2) * sizeof(float), stream);

        bhist2_kernel<<<SB_BLOCKS, SB_THREADS, 0, stream>>>(src, dst, bhist);
        scan_a_kernel<<<R_CH * CC_BLOCKS, 256, 0, stream>>>(bhist, ctmp);
        scan_b_kernel<<<1, 256, 0, stream>>>(ctmp, substart, cstart);
        scan_c_kernel<<<R_CH * CC_BLOCKS, 256, 0, stream>>>(bhist, cstart);
        mscatter2_kernel<<<SB_BLOCKS, SB_THREADS, 0, stream>>>(src, dst, bhist,
                                                               store);

        const int* c_sub = substart;
        const int* c_store = store;
        int* bar_counter = bar;
        int* bar_release = bar + 1;
        void* kargs[] = {
            (void*)&c_sub,       (void*)&c_store,    (void*)&x,
            (void*)&w_self,      (void*)&b_self,     (void*)&w_neigh,
            (void*)&b_neigh,     (void*)&hout,       (void*)&hsum,
            (void*)&bar_counter, (void*)&bar_release};
        hipError_t cerr = hipLaunchCooperativeKernel(
            (const void*)coop_aggr_kernel, dim3(NB), dim3(256), kargs, 0,
            stream);
        if (cerr != hipSuccess) {
            (void)hipGetLastError();  // clear sticky error, use fallback
            aggr_nosync_kernel<<<NB, 256, 0, stream>>>(
                substart, store, x, w_self, b_self, w_neigh, b_neigh, hout,
                hsum);
        }
        head_kernel<<<1, 64, 0, stream>>>(hsum, w_act, b_act, w_prim, b_prim,
                                          out);
    } else {
        float* agg  = (float*)d_ws;
        float* cnt  = agg + (size_t)N_NODES * FEAT;
        float* hsum = cnt + N_NODES;
        const size_t zero_bytes =
            ((size_t)N_NODES * FEAT + N_NODES + HID) * sizeof(float);
        hipMemsetAsync(d_ws, 0, zero_bytes, stream);

        scatter_kernel<<<(N_EDGES + 255) / 256, 256, 0, stream>>>(src, dst, x,
                                                                  agg, cnt);
        node_kernel<<<4096, 256, 0, stream>>>(x, agg, cnt, w_self, b_self,
                                              w_neigh, b_neigh, hout, hsum);
        head_kernel<<<1, 64, 0, stream>>>(hsum, w_act, b_act, w_prim, b_prim,
                                          out);
    }
}